// Round 1
// baseline (3376.572 us; speedup 1.0000x reference)
//
#include <hip/hip_runtime.h>
#include <hip/hip_bf16.h>

typedef __attribute__((ext_vector_type(8))) short bf16x8;
typedef __attribute__((ext_vector_type(4))) float f32x4;

static constexpr int BB = 256;   // batch
static constexpr int TT = 33;    // time (input)
static constexpr int EE = 1024;  // embed
static constexpr int LL = 32;    // scan steps = T-1
static constexpr int NG = 4096;  // 4*E gate rows

__device__ __forceinline__ short f2bf(float f) {
  unsigned u = __builtin_bit_cast(unsigned, f);
  u += 0x7fffu + ((u >> 16) & 1u);   // round-to-nearest-even
  return (short)(u >> 16);
}

__device__ __forceinline__ bf16x8 cvt8(f32x4 a, f32x4 b) {
  bf16x8 r;
  r[0] = f2bf(a[0]); r[1] = f2bf(a[1]); r[2] = f2bf(a[2]); r[3] = f2bf(a[3]);
  r[4] = f2bf(b[0]); r[5] = f2bf(b[1]); r[6] = f2bf(b[2]); r[7] = f2bf(b[3]);
  return r;
}

__device__ __forceinline__ float sigm(float x) { return 1.0f / (1.0f + __expf(-x)); }
__device__ __forceinline__ float tanh_f(float x) { return 1.0f - 2.0f / (__expf(2.0f * x) + 1.0f); }

// One LSTM step. Grid: 256 WGs x 256 threads.
// WG b: e-slice e0 = (b&63)*16 (same slice of each of the 4 gates), rows row0 = (b>>6)*64.
// Wave w (tid>>6) computes gate w for all 64 rows x 16 cols -> 4 MFMA tiles.
// Epilogue exchanges gates through LDS and does the c/h update in-kernel.
__global__ __launch_bounds__(256) void lstm_step(
    const float* __restrict__ x,    // [256][33][1024]
    const float* __restrict__ Wih,  // [32][4096][1024]
    const float* __restrict__ Whh,  // [32][4096][1024]
    short* __restrict__ hbf,        // [256][1024] bf16 (in: h_{t-1}, out: h_t)
    float* __restrict__ c_io,       // [256][1024] fp32 running cell state (d_out c region)
    float* __restrict__ h_out,      // [256][1024] fp32 final h (d_out h region)
    int t, int last)
{
  __shared__ float lds_g[4][64][16];

  const int tid  = threadIdx.x;
  const int lane = tid & 63;
  const int wv   = tid >> 6;      // gate index 0..3 (i,f,g,o)
  const int lr   = lane & 15;     // row (A) / col (B) within 16-tile
  const int kg   = lane >> 4;     // k-group 0..3
  const int e0   = (blockIdx.x & 63) << 4;
  const int row0 = (blockIdx.x >> 6) << 6;

  f32x4 acc0{}, acc1{}, acc2{}, acc3{};

  // ---- phase 1: gates += x_t @ W_ih[t]^T  (K = 1024)
  {
    const float* wp = Wih + (size_t)t * NG * EE + (size_t)(wv * EE + e0 + lr) * EE + (kg << 3);
    const float* a0 = x + ((size_t)(row0 +  0 + lr) * TT + t) * EE + (kg << 3);
    const float* a1 = x + ((size_t)(row0 + 16 + lr) * TT + t) * EE + (kg << 3);
    const float* a2 = x + ((size_t)(row0 + 32 + lr) * TT + t) * EE + (kg << 3);
    const float* a3 = x + ((size_t)(row0 + 48 + lr) * TT + t) * EE + (kg << 3);
#pragma unroll 2
    for (int kc = 0; kc < 32; ++kc) {
      bf16x8 bfr = cvt8(*(const f32x4*)wp, *(const f32x4*)(wp + 4));
      bf16x8 af0 = cvt8(*(const f32x4*)a0, *(const f32x4*)(a0 + 4));
      bf16x8 af1 = cvt8(*(const f32x4*)a1, *(const f32x4*)(a1 + 4));
      bf16x8 af2 = cvt8(*(const f32x4*)a2, *(const f32x4*)(a2 + 4));
      bf16x8 af3 = cvt8(*(const f32x4*)a3, *(const f32x4*)(a3 + 4));
      acc0 = __builtin_amdgcn_mfma_f32_16x16x32_bf16(af0, bfr, acc0, 0, 0, 0);
      acc1 = __builtin_amdgcn_mfma_f32_16x16x32_bf16(af1, bfr, acc1, 0, 0, 0);
      acc2 = __builtin_amdgcn_mfma_f32_16x16x32_bf16(af2, bfr, acc2, 0, 0, 0);
      acc3 = __builtin_amdgcn_mfma_f32_16x16x32_bf16(af3, bfr, acc3, 0, 0, 0);
      wp += 32; a0 += 32; a1 += 32; a2 += 32; a3 += 32;
    }
  }

  // ---- phase 2: gates += h_{t-1} @ W_hh[t]^T  (K = 1024); h_0 == 0 so skip at t==0
  if (t > 0) {
    const float* wp = Whh + (size_t)t * NG * EE + (size_t)(wv * EE + e0 + lr) * EE + (kg << 3);
    const short* h0p = hbf + (size_t)(row0 +  0 + lr) * EE + (kg << 3);
    const short* h1p = hbf + (size_t)(row0 + 16 + lr) * EE + (kg << 3);
    const short* h2p = hbf + (size_t)(row0 + 32 + lr) * EE + (kg << 3);
    const short* h3p = hbf + (size_t)(row0 + 48 + lr) * EE + (kg << 3);
#pragma unroll 2
    for (int kc = 0; kc < 32; ++kc) {
      bf16x8 bfr = cvt8(*(const f32x4*)wp, *(const f32x4*)(wp + 4));
      bf16x8 af0 = *(const bf16x8*)h0p;
      bf16x8 af1 = *(const bf16x8*)h1p;
      bf16x8 af2 = *(const bf16x8*)h2p;
      bf16x8 af3 = *(const bf16x8*)h3p;
      acc0 = __builtin_amdgcn_mfma_f32_16x16x32_bf16(af0, bfr, acc0, 0, 0, 0);
      acc1 = __builtin_amdgcn_mfma_f32_16x16x32_bf16(af1, bfr, acc1, 0, 0, 0);
      acc2 = __builtin_amdgcn_mfma_f32_16x16x32_bf16(af2, bfr, acc2, 0, 0, 0);
      acc3 = __builtin_amdgcn_mfma_f32_16x16x32_bf16(af3, bfr, acc3, 0, 0, 0);
      wp += 32; h0p += 32; h1p += 32; h2p += 32; h3p += 32;
    }
  }

  // ---- epilogue: exchange gates via LDS, fused elementwise LSTM update
  // D layout (verified): col = lane&15, row-in-tile = 4*kg + j
  {
    const f32x4 av[4] = {acc0, acc1, acc2, acc3};
#pragma unroll
    for (int m = 0; m < 4; ++m)
#pragma unroll
      for (int j = 0; j < 4; ++j)
        lds_g[wv][(m << 4) + (kg << 2) + j][lr] = av[m][j];
  }
  __syncthreads();

#pragma unroll
  for (int q = 0; q < 4; ++q) {
    int idx = tid + (q << 8);       // 0..1023 over 64 rows x 16 cols
    int rl = idx >> 4, el = idx & 15;
    float gi = lds_g[0][rl][el];
    float gf = lds_g[1][rl][el];
    float gg = lds_g[2][rl][el];
    float go = lds_g[3][rl][el];
    size_t off = (size_t)(row0 + rl) * EE + (e0 + el);
    float c_old = c_io[off];
    float c_new = sigm(gf) * c_old + sigm(gi) * tanh_f(gg);
    float h_new = sigm(go) * tanh_f(c_new);
    c_io[off] = c_new;
    hbf[off] = f2bf(h_new);
    if (last) h_out[off] = h_new;
  }
}

// init: c0 = x[:,1,:], h0 = 0 (bf16)
__global__ __launch_bounds__(256) void lstm_init(
    const float* __restrict__ x, short* __restrict__ hbf, float* __restrict__ c_io)
{
  int idx = blockIdx.x * 256 + threadIdx.x;   // grid 1024 -> 262144
  int row = idx >> 10, e = idx & 1023;
  c_io[idx] = x[((size_t)row * TT + 1) * EE + e];
  hbf[idx] = 0;
}

__global__ __launch_bounds__(256) void lstm_loss_part(
    const float* __restrict__ h, const float* __restrict__ tgt, float* __restrict__ partials)
{
  __shared__ float lds[4];
  int tid = threadIdx.x;
  float s = 0.f;
  int base = blockIdx.x * 1024 + tid;
#pragma unroll
  for (int q = 0; q < 4; ++q) {
    int idx = base + (q << 8);
    s += fabsf(h[idx] - tgt[idx]);
  }
#pragma unroll
  for (int off = 32; off > 0; off >>= 1) s += __shfl_down(s, off, 64);
  if ((tid & 63) == 0) lds[tid >> 6] = s;
  __syncthreads();
  if (tid == 0) partials[blockIdx.x] = lds[0] + lds[1] + lds[2] + lds[3];
}

__global__ __launch_bounds__(256) void lstm_loss_fin(
    const float* __restrict__ partials, float* __restrict__ out)
{
  __shared__ float lds[4];
  int tid = threadIdx.x;
  float s = partials[tid];
#pragma unroll
  for (int off = 32; off > 0; off >>= 1) s += __shfl_down(s, off, 64);
  if ((tid & 63) == 0) lds[tid >> 6] = s;
  __syncthreads();
  if (tid == 0) out[0] = (lds[0] + lds[1] + lds[2] + lds[3]) * (1.0f / 262144.0f);
}

extern "C" void kernel_launch(void* const* d_in, const int* in_sizes, int n_in,
                              void* d_out, int out_size, void* d_ws, size_t ws_size,
                              hipStream_t stream) {
  const float* x   = (const float*)d_in[0];
  const float* tgt = (const float*)d_in[1];
  const float* Wih = (const float*)d_in[2];
  const float* Whh = (const float*)d_in[3];

  float* out   = (float*)d_out;
  float* h_out = out + 1;                 // [256*1024]
  float* c_io  = out + 1 + BB * EE;       // [256*1024] running cell state lives here

  short* hbf      = (short*)d_ws;                                   // 512 KB bf16 h
  float* partials = (float*)((char*)d_ws + (size_t)BB * EE * 2);    // 256 floats

  lstm_init<<<1024, 256, 0, stream>>>(x, hbf, c_io);
  for (int t = 0; t < LL; ++t)
    lstm_step<<<256, 256, 0, stream>>>(x, Wih, Whh, hbf, c_io, h_out, t, t == LL - 1);
  lstm_loss_part<<<256, 256, 0, stream>>>(h_out, tgt, partials);
  lstm_loss_fin<<<1, 256, 0, stream>>>(partials, out);
}